// Round 17
// baseline (60.091 us; speedup 1.0000x reference)
//
#include <hip/hip_runtime.h>
#include <math.h>

#define EPSBN 1e-5f

constexpr int B_ = 8, C_ = 256, N_ = 4096, IMG_ = 64;
constexpr int HEADS_ = 4, K_ = 16, VV_ = 64, M_ = 11, OC_ = 144;

typedef _Float16 half4 __attribute__((ext_vector_type(4)));
typedef _Float16 half8 __attribute__((ext_vector_type(8)));
typedef __fp16 fp16x2 __attribute__((ext_vector_type(2)));
typedef float f32x4 __attribute__((ext_vector_type(4)));

// workspace layout (float offsets) — r17: SSUM now raw row-sums (atomic),
// LC unnormalized (k_out divides). k_ssum kernel deleted.
constexpr size_t O_WT   = 0;                  // Wf16[144][256] f16 = 18432 fl
constexpr size_t O_BIAS = 18432;              // [144] f32
constexpr size_t O_EMBT = 18688;              // embP 64*48 f16 (slot to 24832)
constexpr size_t O_Q    = 24832;              // QF[8][16cq][4096] uint2 = 1048576 fl
constexpr size_t O_KEYS = O_Q    + 1048576;   // 1073408: raw keys [8][16][4096] f32
constexpr size_t O_SINV = O_KEYS + 524288;    // 1597696: [128] raw sums (atomic)
constexpr size_t O_VP   = 1597952;            // f16 VP[8][64][80][88] = 1802240 fl
constexpr size_t O_LC   = O_VP   + 1802240;   // 3400192: [8][16][64] f32 (atomic, unnormalized)

constexpr int VPROW = 88, VPPLANE = 80 * 88;  // f16 elems

// ---------------- K0: fold BN weights + embP + zero VP/LC/SSUM ------------
__global__ void k_prep(const float* __restrict__ Wq,
                       const float* __restrict__ qg, const float* __restrict__ qb,
                       const float* __restrict__ qm, const float* __restrict__ qv,
                       const float* __restrict__ Wk, const float* __restrict__ Wv,
                       const float* __restrict__ vg, const float* __restrict__ vb,
                       const float* __restrict__ vm, const float* __restrict__ vva,
                       const float* __restrict__ emb, float* __restrict__ ws) {
    int t = threadIdx.x, blk = blockIdx.x;
    if (blk >= 1776) {   // zero LC: 8 blocks x 256 f4 = 8192 fl
        size_t i = (size_t)(blk - 1776) * 256 + t;
        f32x4 z = {0.f, 0.f, 0.f, 0.f};
        *(f32x4*)(ws + O_LC + i * 4) = z;
        return;
    }
    if (blk >= 16) {     // zero VP: 1760 blocks x 256 f4
        size_t i = (size_t)(blk - 16) * 256 + t;
        f32x4 z = {0.f, 0.f, 0.f, 0.f};
        *(f32x4*)(ws + O_VP + i * 4) = z;
        return;
    }
    _Float16* wf = (_Float16*)(ws + O_WT);
    int base = blk * 2304;                       // 16 blocks x 2304 = 36864
#pragma unroll
    for (int i = 0; i < 9; i++) {
        int idx = base + i * 256 + t;
        int o = idx >> 8, c = idx & 255;         // Wf16[o][c]
        float w;
        if (o < 64) {
            float s = qg[o] * rsqrtf(qv[o] + EPSBN);
            w = Wq[o * 256 + c] * s;
        } else if (o < 80) {
            w = Wk[(o - 64) * 256 + c];
        } else {
            int ov = o - 80;
            float s = vg[ov] * rsqrtf(vva[ov] + EPSBN);
            w = Wv[ov * 256 + c] * s;
        }
        wf[idx] = (_Float16)w;
    }
    if (blk == 0) {
        if (t < 144) {
            float bias;
            if (t < 64) {
                float s = qg[t] * rsqrtf(qv[t] + EPSBN);
                bias = qb[t] - qm[t] * s;
            } else if (t < 80) {
                bias = 0.f;
            } else {
                int ov = t - 80;
                float s = vg[ov] * rsqrtf(vva[ov] + EPSBN);
                bias = vb[ov] - vm[ov] * s;
            }
            ws[O_BIAS + t] = bias;
        }
        if (t < 128) ws[O_SINV + t] = 0.f;       // zero atomic sum targets
    }
    if (blk == 15) {
        // embP[l][dp][j] = emb[k=l&15][dy=2dp+(j>>2)][dx=4*(l>>4)+(j&3)]
        _Float16* ef = (_Float16*)(ws + O_EMBT);
        for (int idx = t; idx < 64 * 48; idx += 256) {
            int l = idx / 48, rem = idx % 48;
            int dp = rem >> 3, j = rem & 7;
            int k = l & 15, g = l >> 4;
            int dy = 2 * dp + (j >> 2);
            int dx = 4 * g + (j & 3);
            float v = (dy < 11 && dx < 11) ? emb[k * 121 + dy * 11 + dx] : 0.f;
            ef[idx] = (_Float16)v;
        }
    }
}

// ---------------- K1: MFMA(K=32) q/k/v projection (r14 bit-exact) ---------
__global__ __launch_bounds__(256) void k_proj(const float* __restrict__ x,
                                              const float* __restrict__ wsc,
                                              float* __restrict__ ws) {
    __shared__ uint WL[144 * 68];   // 39168 B
    __shared__ uint XL[64 * 68];    // 17408 B
    int b    = blockIdx.y;
    int pos0 = blockIdx.x * 64;
    int t    = threadIdx.x;
    int w = t >> 6, l = t & 63;
    int g = l >> 4, r = l & 15;

    f32x4 acc[9];
#pragma unroll
    for (int mf = 0; mf < 9; mf++) acc[mf] = (f32x4){0.f, 0.f, 0.f, 0.f};

    const uint* wsrc = (const uint*)(wsc + O_WT);
    const float* xb = x + (size_t)b * C_ * N_ + pos0;
    union u4h { uint4 u; half8 h; };

    for (int kh = 0; kh < 2; kh++) {
        if (kh) __syncthreads();    // WAR: everyone done reading half 0
#pragma unroll
        for (int i = 0; i < 9; i++) {
            int idx = t + i * 256;
            int o = idx >> 4, c4 = idx & 15;
            uint4 wv = *(const uint4*)(wsrc + o * 128 + kh * 64 + c4 * 4);
            *(uint4*)&WL[o * 68 + c4 * 4] = wv;
        }
#pragma unroll
        for (int i = 0; i < 4; i++) {
            int idx = t + i * 256;
            int cl = idx >> 4, p4 = idx & 15;
            float4 a0 = *(const float4*)(xb + (size_t)(2 * (64 * kh + cl)) * N_ + 4 * p4);
            float4 a1 = *(const float4*)(xb + (size_t)(2 * (64 * kh + cl) + 1) * N_ + 4 * p4);
            union { _Float16 h[2]; uint u; } pk;
#pragma unroll
            for (int j = 0; j < 4; j++) {
                float v0 = (j == 0) ? a0.x : (j == 1) ? a0.y : (j == 2) ? a0.z : a0.w;
                float v1 = (j == 0) ? a1.x : (j == 1) ? a1.y : (j == 2) ? a1.z : a1.w;
                pk.h[0] = (_Float16)v0; pk.h[1] = (_Float16)v1;
                XL[(4 * p4 + j) * 68 + cl] = pk.u;
            }
        }
        __syncthreads();

#pragma unroll
        for (int ks = 0; ks < 4; ks++) {
            int cu = 16 * ks + 4 * g;
            u4h bf;
            bf.u = *(const uint4*)&XL[(w * 16 + r) * 68 + cu];
#pragma unroll
            for (int mf = 0; mf < 9; mf++) {
                u4h af;
                af.u = *(const uint4*)&WL[(16 * mf + r) * 68 + cu];
                acc[mf] = __builtin_amdgcn_mfma_f32_16x16x32_f16(af.h, bf.h, acc[mf], 0, 0, 0);
            }
        }
    }

    // epilogue: D[m=16mf+4g+reg][n=pos], pos = pos0 + 16w + r
    int pos = pos0 + w * 16 + r;
#pragma unroll
    for (int mf = 0; mf < 9; mf++) {
        float4 bias4 = *(const float4*)(wsc + O_BIAS + 16 * mf + 4 * g);
        f32x4 a = acc[mf];
        float rv0 = a[0] + bias4.x, rv1 = a[1] + bias4.y;
        float rv2 = a[2] + bias4.z, rv3 = a[3] + bias4.w;
        if (mf < 4) {
            union { fp16x2 h[2]; uint2 u; } pk;
            pk.h[0] = __builtin_amdgcn_cvt_pkrtz(rv0, rv1);
            pk.h[1] = __builtin_amdgcn_cvt_pkrtz(rv2, rv3);
            ((uint2*)(ws + O_Q))[((size_t)(b * 16 + 4 * mf + g)) * N_ + pos] = pk.u;
        } else if (mf == 4) {
            int ch0 = 16 * mf + 4 * g;
            float* kp = ws + O_KEYS + ((size_t)(b * 16 + (ch0 - 64))) * N_ + pos;
            kp[0] = rv0; kp[(size_t)N_] = rv1; kp[2 * (size_t)N_] = rv2; kp[3 * (size_t)N_] = rv3;
        } else {
            int ov = 16 * mf + 4 * g - 80;
            int y = pos >> 6, xx = pos & 63;
            _Float16* vp = (_Float16*)(ws + O_VP) +
                           ((size_t)(b * 64 + ov)) * VPPLANE + (size_t)(y + 8) * VPROW + (xx + 8);
            vp[0] = (_Float16)rv0; vp[VPPLANE] = (_Float16)rv1;
            vp[2 * VPPLANE] = (_Float16)rv2; vp[3 * VPPLANE] = (_Float16)rv3;
        }
    }
}

// ---------------- K3: lam_c partials + fused row-sum (atomic; no k_ssum) --
// ek = exp(key) staged UNNORMALIZED; per-k row sums reduced from LDS and
// atomicAdd'ed into SSUM; LC accumulates unnormalized ek*v (k_out divides).
__global__ __launch_bounds__(256) void k_lamc(float* __restrict__ ws) {
    int b  = blockIdx.x >> 6;
    int ch = blockIdx.x & 63;     // image row
    int n0 = ch * 64;
    __shared__ float ek[16 * 64];   // 4 KB
    int t = threadIdx.x;
    {
        int k = t >> 4, nq = t & 15;
        float4 kv = *(const float4*)(ws + O_KEYS + ((size_t)(b * 16 + k)) * N_ + n0 + 4 * nq);
        float4 e;
        e.x = expf(kv.x); e.y = expf(kv.y); e.z = expf(kv.z); e.w = expf(kv.w);
        *(float4*)&ek[k * 64 + 4 * nq] = e;
        // fused row-sum: reduce over the 16 contiguous lanes of this k
        float s = e.x + e.y + e.z + e.w;
#pragma unroll
        for (int off = 1; off < 16; off <<= 1) s += __shfl_xor(s, off);
        if (nq == 0) atomicAdd(ws + O_SINV + b * 16 + k, s);
    }
    __syncthreads();

    int v  = t & 63;
    int kg = __builtin_amdgcn_readfirstlane(t >> 6);
    float acc[4] = {0.f, 0.f, 0.f, 0.f};
    const _Float16* vp = (const _Float16*)(ws + O_VP) +
                         (size_t)(b * 64 + v) * VPPLANE + (size_t)(ch + 8) * VPROW + 8;
    union U4 { uint4 q; _Float16 h[8]; } u[8];
#pragma unroll
    for (int iu = 0; iu < 8; iu++)
        u[iu].q = *(const uint4*)(vp + 8 * iu);
#pragma unroll
    for (int xq = 0; xq < 16; xq++) {
        float4 e0 = *(const float4*)&ek[(kg * 4 + 0) * 64 + 4 * xq];
        float4 e1 = *(const float4*)&ek[(kg * 4 + 1) * 64 + 4 * xq];
        float4 e2 = *(const float4*)&ek[(kg * 4 + 2) * 64 + 4 * xq];
        float4 e3 = *(const float4*)&ek[(kg * 4 + 3) * 64 + 4 * xq];
        float v0 = (float)u[xq >> 1].h[(xq & 1) * 4 + 0];
        float v1 = (float)u[xq >> 1].h[(xq & 1) * 4 + 1];
        float v2 = (float)u[xq >> 1].h[(xq & 1) * 4 + 2];
        float v3 = (float)u[xq >> 1].h[(xq & 1) * 4 + 3];
        acc[0] += e0.x * v0 + e0.y * v1 + e0.z * v2 + e0.w * v3;
        acc[1] += e1.x * v0 + e1.y * v1 + e1.z * v2 + e1.w * v3;
        acc[2] += e2.x * v0 + e2.y * v1 + e2.z * v2 + e2.w * v3;
        acc[3] += e3.x * v0 + e3.y * v1 + e3.z * v2 + e3.w * v3;
    }
#pragma unroll
    for (int j = 0; j < 4; j++)
        atomicAdd(ws + O_LC + ((size_t)(b * 16 + kg * 4 + j)) * 64 + v, acc[j]);
}

// ---------------- K5: MFMA(K=32) conv + y_p + y_c (v5 + lc normalize) -----
__global__ __launch_bounds__(256, 4) void k_out(const float* __restrict__ wsc,
                                                float* __restrict__ out) {
    __shared__ ushort vt[2][4][19][84];      // 25536 B
    int ytile = blockIdx.x;                  // 0..7 (8 rows each)
    int vc    = blockIdx.y;                  // 0..15 (4 v each)
    int b     = blockIdx.z;
    int y0 = ytile * 8, v0 = vc * 4;
    int t = threadIdx.x;
    int w = t >> 6, l = t & 63;
    int g = l >> 4, nb = l & 15;

    // lam_c: load unnormalized, scale by 1/SSUM[k] per k-slice
    float4 lc4[4];
    float4 ssum4 = *(const float4*)(wsc + O_SINV + b * 16 + 4 * g);
#pragma unroll
    for (int i = 0; i < 4; i++) {
        float inv = 1.f / ((i == 0) ? ssum4.x : (i == 1) ? ssum4.y
                          : (i == 2) ? ssum4.z : ssum4.w);
        float4 lv = *(const float4*)(wsc + O_LC + ((size_t)(b * 16 + 4 * g + i)) * 64 + v0);
        lv.x *= inv; lv.y *= inv; lv.z *= inv; lv.w *= inv;
        lc4[i] = lv;
    }

    union AF { uint4 u; half8 h; } af[6];
    {
        const uint4* ap = (const uint4*)((const _Float16*)(wsc + O_EMBT) + (size_t)l * 48);
#pragma unroll
        for (int dp = 0; dp < 6; dp++) af[dp].u = ap[dp];
    }

    const ushort* vpb = (const ushort*)(wsc + O_VP) + (size_t)(b * 64 + v0) * VPPLANE;
    for (int T = t; T < 1596; T += 256) {
        int v = T / 399, rem = T % 399;       // 399 = 19 rows * 21 quads
        int r = rem / 21, qd = rem % 21;
        const ushort* src = vpb + (size_t)v * VPPLANE + (size_t)(y0 + 3 + r) * VPROW + 4 * qd;
        uint2 u01 = *(const uint2*)src;
        uint2 u23 = *(const uint2*)(src + 4);
        *(uint2*)&vt[0][v][r][4 * qd] = u01;
        uint lo = (u01.x >> 16) | (u01.y << 16);
        uint hi = (u01.y >> 16) | (u23.x << 16);
        *(uint2*)&vt[1][v][r][4 * qd] = make_uint2(lo, hi);
    }
    __syncthreads();

    const uint* vtu = (const uint*)&vt[0][0][0][0];
    const uint2* qfp = (const uint2*)(wsc + O_Q);

#pragma unroll
    for (int xt = 0; xt < 4; xt++) {
        int X = xt * 16 + nb;
        union QH { uint2 u; fp16x2 h[2]; } qh[2][4];
#pragma unroll
        for (int yy2 = 0; yy2 < 2; yy2++) {
            int pos = (y0 + 2 * w + yy2) * 64 + X;
#pragma unroll
            for (int j = 0; j < 4; j++)
                qh[yy2][j].u = qfp[((size_t)(b * 16 + 4 * (g ^ j) + g)) * N_ + pos];
        }
        int wcol = X + 4 * g + 3;
        int cp   = wcol & 1;
        int j0u  = (wcol - cp) >> 1;

#pragma unroll
        for (int v = 0; v < 4; v++) {
            int bwin = ((cp * 4 + v) * 19 + 2 * w) * 42 + j0u;
            uint2 win[13];
#pragma unroll
            for (int i = 0; i < 13; i++) {
                win[i].x = vtu[bwin + 42 * i];
                win[i].y = vtu[bwin + 42 * i + 1];
            }

#pragma unroll
            for (int yy2 = 0; yy2 < 2; yy2++) {
                f32x4 acc = {0.f, 0.f, 0.f, 0.f};
#pragma unroll
                for (int dp = 0; dp < 6; dp++) {
                    union { uint u[4]; half8 h; } bb;
                    bb.u[0] = win[yy2 + 2 * dp].x;
                    bb.u[1] = win[yy2 + 2 * dp].y;
                    bb.u[2] = win[yy2 + 2 * dp + 1].x;
                    bb.u[3] = win[yy2 + 2 * dp + 1].y;
                    acc = __builtin_amdgcn_mfma_f32_16x16x32_f16(af[dp].h, bb.h, acc, 0, 0, 0);
                }
                float d0 = acc[0] + lc4[0][v];
                float d1 = acc[1] + lc4[1][v];
                float d2 = acc[2] + lc4[2][v];
                float d3 = acc[3] + lc4[3][v];
                fp16x2 dlo = __builtin_amdgcn_cvt_pkrtz(d0, d1);
                fp16x2 dhi = __builtin_amdgcn_cvt_pkrtz(d2, d3);
                float ph[4];
#pragma unroll
                for (int j = 0; j < 4; j++)
                    ph[j] = __builtin_amdgcn_fdot2(qh[yy2][j].h[0], dlo,
                            __builtin_amdgcn_fdot2(qh[yy2][j].h[1], dhi, 0.f, false), false);
                float sa = ph[0] + __shfl_xor(ph[1], 16);
                float sb = ph[2] + __shfl_xor(ph[3], 16);
                float o  = sa + __shfl_xor(sb, 32);
                int pos = (y0 + 2 * w + yy2) * 64 + X;
                out[((size_t)(b * 256 + g * 64 + v0 + v)) * N_ + pos] = o;
            }
        }
    }
}

extern "C" void kernel_launch(void* const* d_in, const int* in_sizes, int n_in,
                              void* d_out, int out_size, void* d_ws, size_t ws_size,
                              hipStream_t stream) {
    const float* x   = (const float*)d_in[0];
    const float* Wq  = (const float*)d_in[1];
    const float* qg  = (const float*)d_in[2];
    const float* qb  = (const float*)d_in[3];
    const float* qm  = (const float*)d_in[4];
    const float* qv  = (const float*)d_in[5];
    const float* Wk  = (const float*)d_in[6];
    const float* Wv  = (const float*)d_in[7];
    const float* vg  = (const float*)d_in[8];
    const float* vb  = (const float*)d_in[9];
    const float* vm  = (const float*)d_in[10];
    const float* vva = (const float*)d_in[11];
    const float* emb = (const float*)d_in[12];
    float* ws  = (float*)d_ws;
    float* out = (float*)d_out;

    k_prep<<<1784, 256, 0, stream>>>(Wq, qg, qb, qm, qv, Wk, Wv, vg, vb, vm, vva, emb, ws);
    k_proj<<<dim3(64, 8), 256, 0, stream>>>(x, ws, ws);
    k_lamc<<<512, 256, 0, stream>>>(ws);
    k_out<<<dim3(8, 16, 8), 256, 0, stream>>>(ws, out);
}

// Round 18
// 57.965 us; speedup vs baseline: 1.0367x; 1.0367x over previous
//
#include <hip/hip_runtime.h>
#include <math.h>

#define EPSBN 1e-5f

constexpr int B_ = 8, C_ = 256, N_ = 4096, IMG_ = 64;
constexpr int HEADS_ = 4, K_ = 16, VV_ = 64, M_ = 11, OC_ = 144;

typedef _Float16 half4 __attribute__((ext_vector_type(4)));
typedef _Float16 half8 __attribute__((ext_vector_type(8)));
typedef __fp16 fp16x2 __attribute__((ext_vector_type(2)));
typedef float f32x4 __attribute__((ext_vector_type(4)));

// workspace layout (float offsets) — r16 proven config (58.0 us)
constexpr size_t O_WT   = 0;                  // Wf16[144][256] f16 = 18432 fl
constexpr size_t O_BIAS = 18432;              // [144] f32
constexpr size_t O_EMBT = 18688;              // embP 64*48 f16 (slot to 24832)
constexpr size_t O_Q    = 24832;              // QF[8][16cq][4096] uint2 = 1048576 fl
constexpr size_t O_KEYS = O_Q    + 1048576;   // 1073408: raw keys [8][16][4096] f32
constexpr size_t O_SINV = O_KEYS + 524288;    // 1597696: [128] inv-denominators
constexpr size_t O_VP   = 1597952;            // f16 VP[8][64][80][88] = 1802240 fl
constexpr size_t O_LC   = O_VP   + 1802240;   // 3400192: [8][16][64] f32 (atomic targets)

constexpr int VPROW = 88, VPPLANE = 80 * 88;  // f16 elems

// ---------------- K0: fold BN weights + embP + zero VP/LC (merged) --------
__global__ void k_prep(const float* __restrict__ Wq,
                       const float* __restrict__ qg, const float* __restrict__ qb,
                       const float* __restrict__ qm, const float* __restrict__ qv,
                       const float* __restrict__ Wk, const float* __restrict__ Wv,
                       const float* __restrict__ vg, const float* __restrict__ vb,
                       const float* __restrict__ vm, const float* __restrict__ vva,
                       const float* __restrict__ emb, float* __restrict__ ws) {
    int t = threadIdx.x, blk = blockIdx.x;
    if (blk >= 1776) {   // zero LC: 8 blocks x 256 f4 = 8192 fl
        size_t i = (size_t)(blk - 1776) * 256 + t;
        f32x4 z = {0.f, 0.f, 0.f, 0.f};
        *(f32x4*)(ws + O_LC + i * 4) = z;
        return;
    }
    if (blk >= 16) {     // zero VP: 1760 blocks x 256 f4
        size_t i = (size_t)(blk - 16) * 256 + t;
        f32x4 z = {0.f, 0.f, 0.f, 0.f};
        *(f32x4*)(ws + O_VP + i * 4) = z;
        return;
    }
    _Float16* wf = (_Float16*)(ws + O_WT);
    int base = blk * 2304;                       // 16 blocks x 2304 = 36864
#pragma unroll
    for (int i = 0; i < 9; i++) {
        int idx = base + i * 256 + t;
        int o = idx >> 8, c = idx & 255;         // Wf16[o][c]
        float w;
        if (o < 64) {
            float s = qg[o] * rsqrtf(qv[o] + EPSBN);
            w = Wq[o * 256 + c] * s;
        } else if (o < 80) {
            w = Wk[(o - 64) * 256 + c];
        } else {
            int ov = o - 80;
            float s = vg[ov] * rsqrtf(vva[ov] + EPSBN);
            w = Wv[ov * 256 + c] * s;
        }
        wf[idx] = (_Float16)w;
    }
    if (blk == 0 && t < 144) {
        float bias;
        if (t < 64) {
            float s = qg[t] * rsqrtf(qv[t] + EPSBN);
            bias = qb[t] - qm[t] * s;
        } else if (t < 80) {
            bias = 0.f;
        } else {
            int ov = t - 80;
            float s = vg[ov] * rsqrtf(vva[ov] + EPSBN);
            bias = vb[ov] - vm[ov] * s;
        }
        ws[O_BIAS + t] = bias;
    }
    if (blk == 15) {
        // embP[l][dp][j] = emb[k=l&15][dy=2dp+(j>>2)][dx=4*(l>>4)+(j&3)]
        _Float16* ef = (_Float16*)(ws + O_EMBT);
        for (int idx = t; idx < 64 * 48; idx += 256) {
            int l = idx / 48, rem = idx % 48;
            int dp = rem >> 3, j = rem & 7;
            int k = l & 15, g = l >> 4;
            int dy = 2 * dp + (j >> 2);
            int dx = 4 * g + (j & 3);
            float v = (dy < 11 && dx < 11) ? emb[k * 121 + dy * 11 + dx] : 0.f;
            ef[idx] = (_Float16)v;
        }
    }
}

// ---------------- K1: MFMA(K=32) q/k/v projection -------------------------
__global__ __launch_bounds__(256) void k_proj(const float* __restrict__ x,
                                              const float* __restrict__ wsc,
                                              float* __restrict__ ws) {
    __shared__ uint WL[144 * 68];   // 39168 B
    __shared__ uint XL[64 * 68];    // 17408 B
    int b    = blockIdx.y;
    int pos0 = blockIdx.x * 64;
    int t    = threadIdx.x;
    int w = t >> 6, l = t & 63;
    int g = l >> 4, r = l & 15;

    f32x4 acc[9];
#pragma unroll
    for (int mf = 0; mf < 9; mf++) acc[mf] = (f32x4){0.f, 0.f, 0.f, 0.f};

    const uint* wsrc = (const uint*)(wsc + O_WT);
    const float* xb = x + (size_t)b * C_ * N_ + pos0;
    union u4h { uint4 u; half8 h; };

    for (int kh = 0; kh < 2; kh++) {
        if (kh) __syncthreads();    // WAR: everyone done reading half 0
#pragma unroll
        for (int i = 0; i < 9; i++) {
            int idx = t + i * 256;
            int o = idx >> 4, c4 = idx & 15;
            uint4 wv = *(const uint4*)(wsrc + o * 128 + kh * 64 + c4 * 4);
            *(uint4*)&WL[o * 68 + c4 * 4] = wv;
        }
#pragma unroll
        for (int i = 0; i < 4; i++) {
            int idx = t + i * 256;
            int cl = idx >> 4, p4 = idx & 15;
            float4 a0 = *(const float4*)(xb + (size_t)(2 * (64 * kh + cl)) * N_ + 4 * p4);
            float4 a1 = *(const float4*)(xb + (size_t)(2 * (64 * kh + cl) + 1) * N_ + 4 * p4);
            union { _Float16 h[2]; uint u; } pk;
#pragma unroll
            for (int j = 0; j < 4; j++) {
                float v0 = (j == 0) ? a0.x : (j == 1) ? a0.y : (j == 2) ? a0.z : a0.w;
                float v1 = (j == 0) ? a1.x : (j == 1) ? a1.y : (j == 2) ? a1.z : a1.w;
                pk.h[0] = (_Float16)v0; pk.h[1] = (_Float16)v1;
                XL[(4 * p4 + j) * 68 + cl] = pk.u;
            }
        }
        __syncthreads();

#pragma unroll
        for (int ks = 0; ks < 4; ks++) {
            int cu = 16 * ks + 4 * g;
            u4h bf;
            bf.u = *(const uint4*)&XL[(w * 16 + r) * 68 + cu];
#pragma unroll
            for (int mf = 0; mf < 9; mf++) {
                u4h af;
                af.u = *(const uint4*)&WL[(16 * mf + r) * 68 + cu];
                acc[mf] = __builtin_amdgcn_mfma_f32_16x16x32_f16(af.h, bf.h, acc[mf], 0, 0, 0);
            }
        }
    }

    // epilogue: D[m=16mf+4g+reg][n=pos], pos = pos0 + 16w + r
    int pos = pos0 + w * 16 + r;
#pragma unroll
    for (int mf = 0; mf < 9; mf++) {
        float4 bias4 = *(const float4*)(wsc + O_BIAS + 16 * mf + 4 * g);
        f32x4 a = acc[mf];
        float rv0 = a[0] + bias4.x, rv1 = a[1] + bias4.y;
        float rv2 = a[2] + bias4.z, rv3 = a[3] + bias4.w;
        if (mf < 4) {
            union { fp16x2 h[2]; uint2 u; } pk;
            pk.h[0] = __builtin_amdgcn_cvt_pkrtz(rv0, rv1);
            pk.h[1] = __builtin_amdgcn_cvt_pkrtz(rv2, rv3);
            ((uint2*)(ws + O_Q))[((size_t)(b * 16 + 4 * mf + g)) * N_ + pos] = pk.u;
        } else if (mf == 4) {
            int ch0 = 16 * mf + 4 * g;
            float* kp = ws + O_KEYS + ((size_t)(b * 16 + (ch0 - 64))) * N_ + pos;
            kp[0] = rv0; kp[(size_t)N_] = rv1; kp[2 * (size_t)N_] = rv2; kp[3 * (size_t)N_] = rv3;
        } else {
            int ov = 16 * mf + 4 * g - 80;
            int y = pos >> 6, xx = pos & 63;
            _Float16* vp = (_Float16*)(ws + O_VP) +
                           ((size_t)(b * 64 + ov)) * VPPLANE + (size_t)(y + 8) * VPROW + (xx + 8);
            vp[0] = (_Float16)rv0; vp[VPPLANE] = (_Float16)rv1;
            vp[2 * VPPLANE] = (_Float16)rv2; vp[3 * VPPLANE] = (_Float16)rv3;
        }
    }
}

// ---------------- K2: softmax denominator (no max-sub; keys ~ N(0,1)) -----
__global__ __launch_bounds__(256) void k_ssum(float* __restrict__ ws) {
    int row = blockIdx.x;   // b*16 + k
    const float* src = ws + O_KEYS + (size_t)row * N_;
    int t = threadIdx.x;
    float s = 0.f;
#pragma unroll
    for (int i = 0; i < 4; i++) {
        float4 r = *(const float4*)(src + i * 1024 + t * 4);
        s += expf(r.x) + expf(r.y) + expf(r.z) + expf(r.w);
    }
    for (int off = 32; off > 0; off >>= 1) s += __shfl_xor(s, off);
    __shared__ float reds[4];
    if ((t & 63) == 0) reds[t >> 6] = s;
    __syncthreads();
    if (t == 0)
        ws[O_SINV + row] = 1.f / (reds[0] + reds[1] + reds[2] + reds[3]);
}

// ---------------- K3: lam_c partials (fused exp; VP reads; atomic LC) -----
__global__ __launch_bounds__(256) void k_lamc(float* __restrict__ ws) {
    int b  = blockIdx.x >> 6;
    int ch = blockIdx.x & 63;     // image row
    int n0 = ch * 64;
    __shared__ float ek[16 * 64];   // 4 KB
    int t = threadIdx.x;
    {
        int k = t >> 4, nq = t & 15;
        float4 kv = *(const float4*)(ws + O_KEYS + ((size_t)(b * 16 + k)) * N_ + n0 + 4 * nq);
        float is = ws[O_SINV + b * 16 + k];
        float4 e;
        e.x = expf(kv.x) * is; e.y = expf(kv.y) * is;
        e.z = expf(kv.z) * is; e.w = expf(kv.w) * is;
        *(float4*)&ek[k * 64 + 4 * nq] = e;
    }
    __syncthreads();

    int v  = t & 63;
    int kg = __builtin_amdgcn_readfirstlane(t >> 6);
    float acc[4] = {0.f, 0.f, 0.f, 0.f};
    const _Float16* vp = (const _Float16*)(ws + O_VP) +
                         (size_t)(b * 64 + v) * VPPLANE + (size_t)(ch + 8) * VPROW + 8;
    union U4 { uint4 q; _Float16 h[8]; } u[8];
#pragma unroll
    for (int iu = 0; iu < 8; iu++)
        u[iu].q = *(const uint4*)(vp + 8 * iu);
#pragma unroll
    for (int xq = 0; xq < 16; xq++) {
        float4 e0 = *(const float4*)&ek[(kg * 4 + 0) * 64 + 4 * xq];
        float4 e1 = *(const float4*)&ek[(kg * 4 + 1) * 64 + 4 * xq];
        float4 e2 = *(const float4*)&ek[(kg * 4 + 2) * 64 + 4 * xq];
        float4 e3 = *(const float4*)&ek[(kg * 4 + 3) * 64 + 4 * xq];
        float v0 = (float)u[xq >> 1].h[(xq & 1) * 4 + 0];
        float v1 = (float)u[xq >> 1].h[(xq & 1) * 4 + 1];
        float v2 = (float)u[xq >> 1].h[(xq & 1) * 4 + 2];
        float v3 = (float)u[xq >> 1].h[(xq & 1) * 4 + 3];
        acc[0] += e0.x * v0 + e0.y * v1 + e0.z * v2 + e0.w * v3;
        acc[1] += e1.x * v0 + e1.y * v1 + e1.z * v2 + e1.w * v3;
        acc[2] += e2.x * v0 + e2.y * v1 + e2.z * v2 + e2.w * v3;
        acc[3] += e3.x * v0 + e3.y * v1 + e3.z * v2 + e3.w * v3;
    }
#pragma unroll
    for (int j = 0; j < 4; j++)
        atomicAdd(ws + O_LC + ((size_t)(b * 16 + kg * 4 + j)) * 64 + v, acc[j]);
}

// ---------------- K5: MFMA(K=32) conv + y_p + y_c (v5) --------------------
__global__ __launch_bounds__(256, 4) void k_out(const float* __restrict__ wsc,
                                                float* __restrict__ out) {
    __shared__ ushort vt[2][4][19][84];      // 25536 B
    int ytile = blockIdx.x;                  // 0..7 (8 rows each)
    int vc    = blockIdx.y;                  // 0..15 (4 v each)
    int b     = blockIdx.z;
    int y0 = ytile * 8, v0 = vc * 4;
    int t = threadIdx.x;
    int w = t >> 6, l = t & 63;
    int g = l >> 4, nb = l & 15;

    float4 lc4[4];
#pragma unroll
    for (int i = 0; i < 4; i++)
        lc4[i] = *(const float4*)(wsc + O_LC + ((size_t)(b * 16 + 4 * g + i)) * 64 + v0);

    union AF { uint4 u; half8 h; } af[6];
    {
        const uint4* ap = (const uint4*)((const _Float16*)(wsc + O_EMBT) + (size_t)l * 48);
#pragma unroll
        for (int dp = 0; dp < 6; dp++) af[dp].u = ap[dp];
    }

    const ushort* vpb = (const ushort*)(wsc + O_VP) + (size_t)(b * 64 + v0) * VPPLANE;
    for (int T = t; T < 1596; T += 256) {
        int v = T / 399, rem = T % 399;       // 399 = 19 rows * 21 quads
        int r = rem / 21, qd = rem % 21;
        const ushort* src = vpb + (size_t)v * VPPLANE + (size_t)(y0 + 3 + r) * VPROW + 4 * qd;
        uint2 u01 = *(const uint2*)src;
        uint2 u23 = *(const uint2*)(src + 4);
        *(uint2*)&vt[0][v][r][4 * qd] = u01;
        uint lo = (u01.x >> 16) | (u01.y << 16);
        uint hi = (u01.y >> 16) | (u23.x << 16);
        *(uint2*)&vt[1][v][r][4 * qd] = make_uint2(lo, hi);
    }
    __syncthreads();

    const uint* vtu = (const uint*)&vt[0][0][0][0];
    const uint2* qfp = (const uint2*)(wsc + O_Q);

#pragma unroll
    for (int xt = 0; xt < 4; xt++) {
        int X = xt * 16 + nb;
        union QH { uint2 u; fp16x2 h[2]; } qh[2][4];
#pragma unroll
        for (int yy2 = 0; yy2 < 2; yy2++) {
            int pos = (y0 + 2 * w + yy2) * 64 + X;
#pragma unroll
            for (int j = 0; j < 4; j++)
                qh[yy2][j].u = qfp[((size_t)(b * 16 + 4 * (g ^ j) + g)) * N_ + pos];
        }
        int wcol = X + 4 * g + 3;
        int cp   = wcol & 1;
        int j0u  = (wcol - cp) >> 1;

#pragma unroll
        for (int v = 0; v < 4; v++) {
            int bwin = ((cp * 4 + v) * 19 + 2 * w) * 42 + j0u;
            uint2 win[13];
#pragma unroll
            for (int i = 0; i < 13; i++) {
                win[i].x = vtu[bwin + 42 * i];
                win[i].y = vtu[bwin + 42 * i + 1];
            }

#pragma unroll
            for (int yy2 = 0; yy2 < 2; yy2++) {
                f32x4 acc = {0.f, 0.f, 0.f, 0.f};
#pragma unroll
                for (int dp = 0; dp < 6; dp++) {
                    union { uint u[4]; half8 h; } bb;
                    bb.u[0] = win[yy2 + 2 * dp].x;
                    bb.u[1] = win[yy2 + 2 * dp].y;
                    bb.u[2] = win[yy2 + 2 * dp + 1].x;
                    bb.u[3] = win[yy2 + 2 * dp + 1].y;
                    acc = __builtin_amdgcn_mfma_f32_16x16x32_f16(af[dp].h, bb.h, acc, 0, 0, 0);
                }
                float d0 = acc[0] + lc4[0][v];
                float d1 = acc[1] + lc4[1][v];
                float d2 = acc[2] + lc4[2][v];
                float d3 = acc[3] + lc4[3][v];
                fp16x2 dlo = __builtin_amdgcn_cvt_pkrtz(d0, d1);
                fp16x2 dhi = __builtin_amdgcn_cvt_pkrtz(d2, d3);
                float ph[4];
#pragma unroll
                for (int j = 0; j < 4; j++)
                    ph[j] = __builtin_amdgcn_fdot2(qh[yy2][j].h[0], dlo,
                            __builtin_amdgcn_fdot2(qh[yy2][j].h[1], dhi, 0.f, false), false);
                float sa = ph[0] + __shfl_xor(ph[1], 16);
                float sb = ph[2] + __shfl_xor(ph[3], 16);
                float o  = sa + __shfl_xor(sb, 32);
                int pos = (y0 + 2 * w + yy2) * 64 + X;
                out[((size_t)(b * 256 + g * 64 + v0 + v)) * N_ + pos] = o;
            }
        }
    }
}

extern "C" void kernel_launch(void* const* d_in, const int* in_sizes, int n_in,
                              void* d_out, int out_size, void* d_ws, size_t ws_size,
                              hipStream_t stream) {
    const float* x   = (const float*)d_in[0];
    const float* Wq  = (const float*)d_in[1];
    const float* qg  = (const float*)d_in[2];
    const float* qb  = (const float*)d_in[3];
    const float* qm  = (const float*)d_in[4];
    const float* qv  = (const float*)d_in[5];
    const float* Wk  = (const float*)d_in[6];
    const float* Wv  = (const float*)d_in[7];
    const float* vg  = (const float*)d_in[8];
    const float* vb  = (const float*)d_in[9];
    const float* vm  = (const float*)d_in[10];
    const float* vva = (const float*)d_in[11];
    const float* emb = (const float*)d_in[12];
    float* ws  = (float*)d_ws;
    float* out = (float*)d_out;

    k_prep<<<1784, 256, 0, stream>>>(Wq, qg, qb, qm, qv, Wk, Wv, vg, vb, vm, vva, emb, ws);
    k_proj<<<dim3(64, 8), 256, 0, stream>>>(x, ws, ws);
    k_ssum<<<128, 256, 0, stream>>>(ws);
    k_lamc<<<512, 256, 0, stream>>>(ws);
    k_out<<<dim3(8, 16, 8), 256, 0, stream>>>(ws, out);
}